// Round 4
// baseline (293.212 us; speedup 1.0000x reference)
//
#include <hip/hip_runtime.h>
#include <hip/hip_bf16.h>

#define EPSV 1e-3f

__device__ __forceinline__ float rcp_fast(float x){ return __builtin_amdgcn_rcpf(x); }
__device__ __forceinline__ float sigm(float x){
    return rcp_fast(1.f + __expf(-x));
}

#define KEEP(x) asm volatile("" : "+v"(x))

// ds_swizzle BitMode: new_lane = ((lane & AND) | OR)  (within each 32-lane group)
template<int OR, int AND>
__device__ __forceinline__ float swz(float v){
    return __int_as_float(__builtin_amdgcn_ds_swizzle(__float_as_int(v), (OR << 5) | AND));
}
// Broadcast h of unit e to all lanes: each 8-lane chunk holds units 0..7.
#define BCAST8(dst, src) do { \
    dst[0]=swz<0,0x18>(src); dst[1]=swz<1,0x18>(src); dst[2]=swz<2,0x18>(src); dst[3]=swz<3,0x18>(src); \
    dst[4]=swz<4,0x18>(src); dst[5]=swz<5,0x18>(src); dst[6]=swz<6,0x18>(src); dst[7]=swz<7,0x18>(src); } while(0)

// legacy 8-lane broadcast (K2)
template<int K>
__device__ __forceinline__ float bc8(float v){
    return __int_as_float(__builtin_amdgcn_ds_swizzle(__float_as_int(v), (K << 5) | 0x18));
}
#define BC8_ALL(dst, src) do { \
    dst[0]=bc8<0>(src); dst[1]=bc8<1>(src); dst[2]=bc8<2>(src); dst[3]=bc8<3>(src); \
    dst[4]=bc8<4>(src); dst[5]=bc8<5>(src); dst[6]=bc8<6>(src); dst[7]=bc8<7>(src); } while(0)

// ---------------- K1: stage-1 LSTM (tanh), 32 lanes per sample ----------------
// lane owns ONE gate column (col = tid&31): weights/lane = 16+8+1 floats ->
// total live ~55 regs, fits the allocator's 64-reg/8-wave target natively
// (R1-R3 evidence: 8-lane layout with ~150-reg demand got remat'd to 64 regs
// with in-loop weight reloads; allocator ignores launch-bounds cap).
__global__ __launch_bounds__(256, 4) void k1_lstm0(
    const float* __restrict__ noise, const float* __restrict__ W0,
    const float* __restrict__ U0, const float* __restrict__ b0,
    float* __restrict__ Hbuf, float* __restrict__ Cbuf, double* __restrict__ stats1)
{
    const int tid = threadIdx.x;
    const int col = tid & 31;       // gate column
    const int q   = tid & 7;        // unit
    const int gt  = col >> 3;       // 0=i,1=f,2=g(cell),3=o
    const size_t s = (size_t)blockIdx.x * 8 + (tid >> 5);

    float wcol[16], ucol[8];
    #pragma unroll
    for (int f = 0; f < 16; ++f) wcol[f] = W0[f*32 + col];
    #pragma unroll
    for (int e = 0; e < 8; ++e)  ucol[e] = U0[e*32 + col];
    float bias = b0[col];
    #pragma unroll
    for (int f = 0; f < 16; ++f) KEEP(wcol[f]);
    #pragma unroll
    for (int e = 0; e < 8; ++e)  KEEP(ucol[e]);
    KEEP(bias);
    // unified activation: gate g -> tanh(z)=2*sigm(2z)-1 ; others sigm(z)
    const float ckn = (gt == 2) ? -2.f : -1.f;   // exp arg scale
    const float am  = (gt == 2) ?  2.f :  1.f;
    const float an  = (gt == 2) ? -1.f :  0.f;

    const float4* __restrict__ xrow = reinterpret_cast<const float4*>(noise + s * 512);
    float h = 0.f, c = 0.f, hall[8];
    #pragma unroll
    for (int e = 0; e < 8; ++e) hall[e] = 0.f;

    #pragma unroll 2
    for (int t = 0; t < 32; ++t){
        float4 q0 = xrow[t*4+0], q1 = xrow[t*4+1], q2 = xrow[t*4+2], q3 = xrow[t*4+3];
        float z = bias;
        #pragma unroll
        for (int e = 0; e < 8; ++e) z = fmaf(hall[e], ucol[e], z);
        const float x[16] = {q0.x,q0.y,q0.z,q0.w, q1.x,q1.y,q1.z,q1.w,
                             q2.x,q2.y,q2.z,q2.w, q3.x,q3.y,q3.z,q3.w};
        #pragma unroll
        for (int f = 0; f < 16; ++f) z = fmaf(x[f], wcol[f], z);
        const float a = fmaf(rcp_fast(1.f + __expf(z * ckn)), am, an);
        // gather the 4 activated gates of unit q (lanes q, 8+q, 16+q, 24+q)
        const float ai = swz< 0,7>(a), af = swz< 8,7>(a), ag = swz<16,7>(a), ao = swz<24,7>(a);
        c = fmaf(af, c, ai * ag);
        const float s2 = rcp_fast(1.f + __expf(-2.f * c));     // tanh(c)=2*s2-1
        h = ao * (2.f * s2 - 1.f);
        BCAST8(hall, h);
    }
    if (((tid >> 3) & 3) == 0){                 // one replica chunk writes
        Hbuf[s*8 + q] = h;
        Cbuf[s*8 + q] = c;
    }

    // BN1 stats (values replicated x4 within 32-group -> scale by 0.25)
    float v0 = h, v1 = h*h, v2 = c, v3 = c*c;
    v0 += __shfl_xor(v0,8); v0 += __shfl_xor(v0,16); v0 += __shfl_xor(v0,32);
    v1 += __shfl_xor(v1,8); v1 += __shfl_xor(v1,16); v1 += __shfl_xor(v1,32);
    v2 += __shfl_xor(v2,8); v2 += __shfl_xor(v2,16); v2 += __shfl_xor(v2,32);
    v3 += __shfl_xor(v3,8); v3 += __shfl_xor(v3,16); v3 += __shfl_xor(v3,32);
    __shared__ float red[4][4][8];
    const int w = tid >> 6;
    if ((tid & 63) < 8){
        red[0][w][q] = v0 * 0.25f; red[1][w][q] = v1 * 0.25f;
        red[2][w][q] = v2 * 0.25f; red[3][w][q] = v3 * 0.25f;
    }
    __syncthreads();
    if (tid < 32){
        const int st = tid >> 3, dd = tid & 7;
        float acc = red[st][0][dd] + red[st][1][dd] + red[st][2][dd] + red[st][3][dd];
        atomicAdd(stats1 + st*8 + dd, (double)acc);
    }
}

// ---------------- K2: BN1-apply + 14-step AR LSTM (relu), BN3 sums only -------
// (8 lanes/sample; register demand ~55 already fits -> unchanged)
__global__ __launch_bounds__(256) void k2_ar(
    const float* __restrict__ Hbuf, const float* __restrict__ Cbuf,
    const double* __restrict__ stats1,
    const float* __restrict__ gamma_h, const float* __restrict__ beta_h,
    const float* __restrict__ gamma_c, const float* __restrict__ beta_c,
    const float* __restrict__ W1, const float* __restrict__ U1, const float* __restrict__ b1,
    double* __restrict__ stats3, int B)
{
    const int tid = threadIdx.x;
    const int d = tid & 7;
    const double invB = 1.0 / (double)B;
    const float meanH = (float)(stats1[d]      * invB);
    const float eH2   = (float)(stats1[8 + d]  * invB);
    const float meanC = (float)(stats1[16 + d] * invB);
    const float eC2   = (float)(stats1[24 + d] * invB);
    const float aH = gamma_h[d] * rsqrtf(eH2 - meanH*meanH + EPSV);
    const float aC = gamma_c[d] * rsqrtf(eC2 - meanC*meanC + EPSV);
    const float bH = beta_h[d] - meanH*aH;
    const float bC = beta_c[d] - meanC*aC;
    float h = fmaf(Hbuf[(size_t)blockIdx.x*256 + tid], aH, bH);
    float c = fmaf(Cbuf[(size_t)blockIdx.x*256 + tid], aC, bC);

    float wc[8][4], bcv[4];
    #pragma unroll
    for (int g = 0; g < 4; ++g) bcv[g] = b1[8*g + d];
    #pragma unroll
    for (int e = 0; e < 8; ++e)
        #pragma unroll
        for (int g = 0; g < 4; ++g) wc[e][g] = W1[e*32 + 8*g + d] + U1[e*32 + 8*g + d];

    float s1 = 0.f, s2 = 0.f;
    #pragma unroll
    for (int r = 0; r < 14; ++r){
        float hall[8]; BC8_ALL(hall, h);
        float z[4] = {bcv[0], bcv[1], bcv[2], bcv[3]};
        #pragma unroll
        for (int e = 0; e < 8; ++e)
            #pragma unroll
            for (int g = 0; g < 4; ++g) z[g] = fmaf(hall[e], wc[e][g], z[g]);
        c = sigm(z[1])*c + sigm(z[0])*fmaxf(z[2], 0.f);
        h = sigm(z[3])*fmaxf(c, 0.f);
        s1 += h; s2 = fmaf(h, h, s2);
    }
    s1 += __shfl_down(s1,32); s1 += __shfl_down(s1,16); s1 += __shfl_down(s1,8);
    s2 += __shfl_down(s2,32); s2 += __shfl_down(s2,16); s2 += __shfl_down(s2,8);
    __shared__ float red[2][4][8];
    const int w = tid >> 6;
    if ((tid & 63) < 8){ red[0][w][d] = s1; red[1][w][d] = s2; }
    __syncthreads();
    if (tid < 16){
        const int st = tid >> 3, dd = tid & 7;
        float acc = red[st][0][dd] + red[st][1][dd] + red[st][2][dd] + red[st][3][dd];
        atomicAdd(stats3 + st*8 + dd, (double)acc);
    }
}

// ---------------- K3: AR replay + BN3 + output LSTM, 32 lanes per sample ------
__global__ __launch_bounds__(256, 4) void k3_out(
    const float* __restrict__ Hbuf, const float* __restrict__ Cbuf,
    const double* __restrict__ stats1, const double* __restrict__ stats3,
    const float* __restrict__ gamma_h, const float* __restrict__ beta_h,
    const float* __restrict__ gamma_c, const float* __restrict__ beta_c,
    const float* __restrict__ W1, const float* __restrict__ U1, const float* __restrict__ b1,
    const float* __restrict__ gamma3, const float* __restrict__ beta3,
    const float* __restrict__ W2, const float* __restrict__ U2, const float* __restrict__ b2,
    float* __restrict__ out, int B)
{
    const int tid = threadIdx.x;
    const int col = tid & 31;
    const int q   = tid & 7;
    const int gt  = col >> 3;
    const size_t s = (size_t)blockIdx.x * 8 + (tid >> 5);

    const double invB = 1.0 / (double)B;
    const float meanH = (float)(stats1[q]      * invB);
    const float eH2   = (float)(stats1[8 + q]  * invB);
    const float meanC = (float)(stats1[16 + q] * invB);
    const float eC2   = (float)(stats1[24 + q] * invB);
    const float aH = gamma_h[q] * rsqrtf(eH2 - meanH*meanH + EPSV);
    const float aC = gamma_c[q] * rsqrtf(eC2 - meanC*meanC + EPSV);
    float h = fmaf(Hbuf[s*8 + q], aH, beta_h[q] - meanH*aH);
    float c = fmaf(Cbuf[s*8 + q], aC, beta_c[q] - meanC*aC);

    float wsum[8];
    #pragma unroll
    for (int e = 0; e < 8; ++e) wsum[e] = W1[e*32 + col] + U1[e*32 + col];
    const float bias1 = b1[col];
    const bool is_cell = (gt == 2);

    float hall[8]; BCAST8(hall, h);
    float barh[14];
    #pragma unroll
    for (int r = 0; r < 14; ++r){
        float z = bias1;
        #pragma unroll
        for (int e = 0; e < 8; ++e) z = fmaf(hall[e], wsum[e], z);
        const float a = is_cell ? fmaxf(z, 0.f) : sigm(z);
        const float ai = swz< 0,7>(a), af = swz< 8,7>(a), ag = swz<16,7>(a), ao = swz<24,7>(a);
        c = fmaf(af, c, ai * ag);
        h = ao * fmaxf(c, 0.f);
        barh[r] = h;
        BCAST8(hall, h);
    }
    // BN3 over (B, ROWS), per unit q
    const double invN = 1.0 / ((double)B * 14.0);
    const float mean3 = (float)(stats3[q]     * invN);
    const float e32   = (float)(stats3[8 + q] * invN);
    const float a3 = gamma3[q] * rsqrtf(e32 - mean3*mean3 + EPSV);
    const float b3 = beta3[q] - mean3*a3;
    #pragma unroll
    for (int r = 0; r < 14; ++r) barh[r] = fmaf(barh[r], a3, b3);

    // output LSTM (D=8 -> Do=4): 16 gate cols, lanes 16..31 of each group duplicate
    const int col2 = tid & 15;
    const int gt2  = col2 >> 2;
    float w2col[8], u2col[4];
    #pragma unroll
    for (int e = 0; e < 8; ++e) w2col[e] = W2[e*16 + col2];
    #pragma unroll
    for (int e = 0; e < 4; ++e) u2col[e] = U2[e*16 + col2];
    const float bias2 = b2[col2];
    const bool is_cell2 = (gt2 == 2);

    float ho = 0.f, co = 0.f;
    const size_t obase = s * 56;
    #pragma unroll
    for (int r = 0; r < 14; ++r){
        float z = bias2;
        // bars row = barh[13-r] broadcast per unit e (each 8-chunk holds units 0..7)
        #pragma unroll
        for (int e = 0; e < 8; ++e){
            float be;
            if (e==0) be=swz<0,0x18>(barh[13-r]); else if (e==1) be=swz<1,0x18>(barh[13-r]);
            else if (e==2) be=swz<2,0x18>(barh[13-r]); else if (e==3) be=swz<3,0x18>(barh[13-r]);
            else if (e==4) be=swz<4,0x18>(barh[13-r]); else if (e==5) be=swz<5,0x18>(barh[13-r]);
            else if (e==6) be=swz<6,0x18>(barh[13-r]); else be=swz<7,0x18>(barh[13-r]);
            z = fmaf(be, w2col[e], z);
        }
        // previous ho of units 0..3: holder lane = (lane&0x10)|e
        {
            const float h0v = swz<0,0x10>(ho), h1v = swz<1,0x10>(ho),
                        h2v = swz<2,0x10>(ho), h3v = swz<3,0x10>(ho);
            z = fmaf(h0v, u2col[0], z); z = fmaf(h1v, u2col[1], z);
            z = fmaf(h2v, u2col[2], z); z = fmaf(h3v, u2col[3], z);
        }
        const float a = is_cell2 ? fmaxf(z, 0.f) : sigm(z);
        // gather 4 gates of unit q2 within the 16-lane group: keep bits {0,1,4}
        const float ai = swz< 0,0x13>(a), af = swz< 4,0x13>(a),
                    ag = swz< 8,0x13>(a), ao = swz<12,0x13>(a);
        co = fmaf(af, co, ai * ag);
        ho = ao * fmaxf(co, 0.f);
        if ((tid & 31) < 4) out[obase + r*4 + (tid & 3)] = ho;
    }
}

extern "C" void kernel_launch(void* const* d_in, const int* in_sizes, int n_in,
                              void* d_out, int out_size, void* d_ws, size_t ws_size,
                              hipStream_t stream)
{
    const float* noise   = (const float*)d_in[0];
    const float* W0      = (const float*)d_in[1];
    const float* U0      = (const float*)d_in[2];
    const float* b0      = (const float*)d_in[3];
    const float* gamma_h = (const float*)d_in[4];
    const float* beta_h  = (const float*)d_in[5];
    const float* gamma_c = (const float*)d_in[6];
    const float* beta_c  = (const float*)d_in[7];
    const float* W1      = (const float*)d_in[8];
    const float* U1      = (const float*)d_in[9];
    const float* b1      = (const float*)d_in[10];
    const float* gamma3  = (const float*)d_in[11];
    const float* beta3   = (const float*)d_in[12];
    const float* W2      = (const float*)d_in[13];
    const float* U2      = (const float*)d_in[14];
    const float* b2      = (const float*)d_in[15];

    const int B = in_sizes[0] / (32 * 16);   // 65536
    double* stats1 = (double*)d_ws;          // 32 doubles
    double* stats3 = stats1 + 32;            // 16 doubles
    float* Hbuf = (float*)((char*)d_ws + 512);
    float* Cbuf = Hbuf + (size_t)B * 8;

    hipMemsetAsync(d_ws, 0, 48 * sizeof(double), stream);
    k1_lstm0<<<B/8, 256, 0, stream>>>(noise, W0, U0, b0, Hbuf, Cbuf, stats1);
    k2_ar<<<B/32, 256, 0, stream>>>(Hbuf, Cbuf, stats1, gamma_h, beta_h, gamma_c, beta_c,
                                    W1, U1, b1, stats3, B);
    k3_out<<<B/8, 256, 0, stream>>>(Hbuf, Cbuf, stats1, stats3, gamma_h, beta_h, gamma_c, beta_c,
                                    W1, U1, b1, gamma3, beta3, W2, U2, b2, (float*)d_out, B);
}

// Round 5
// 154.225 us; speedup vs baseline: 1.9012x; 1.9012x over previous
//
#include <hip/hip_runtime.h>
#include <hip/hip_bf16.h>

#define EPSV 1e-3f

__device__ __forceinline__ float rcp_fast(float x){ return __builtin_amdgcn_rcpf(x); }
// |z| is bounded (~<10) in this model: no clamps needed.
__device__ __forceinline__ float sigm(float x){
    return rcp_fast(1.f + __expf(-x));
}
__device__ __forceinline__ float tanh_fast(float x){
    float e = __expf(2.f * x);
    return 1.f - 2.f * rcp_fast(e + 1.f);
}

// Insurance against rematerialization of invariant loads (R2/R3 evidence:
// loads got re-fetched in-loop; R4: KEEP alone made the spiller use scratch).
// Real fix is amdgpu_waves_per_eu(2,2): occupancy TARGET 2 -> 256-reg budget.
#define KEEP(x) asm volatile("" : "+v"(x))

// Broadcast from lane (group_base + K) within an aligned 8-lane group.
// BitMode swizzle: and=0x18 keeps bits 3-4 (group id within 32-half), or=K sets bits 0-2.
template<int K>
__device__ __forceinline__ float bc8(float v){
    return __int_as_float(__builtin_amdgcn_ds_swizzle(__float_as_int(v), (K << 5) | 0x18));
}
#define BC8_ALL(dst, src) do { \
    dst[0]=bc8<0>(src); dst[1]=bc8<1>(src); dst[2]=bc8<2>(src); dst[3]=bc8<3>(src); \
    dst[4]=bc8<4>(src); dst[5]=bc8<5>(src); dst[6]=bc8<6>(src); dst[7]=bc8<7>(src); } while(0)

// ---------------- K1: stage-1 LSTM (tanh), 8 lanes per sample ----------------
// lane = sib*8 + d ; lane owns hidden unit d (gate columns {d, 8+d, 16+d, 24+d}).
__global__ __launch_bounds__(256)
__attribute__((amdgpu_waves_per_eu(2, 2)))
void k1_lstm0(
    const float* __restrict__ noise, const float* __restrict__ W0,
    const float* __restrict__ U0, const float* __restrict__ b0,
    float* __restrict__ Hbuf, float* __restrict__ Cbuf, double* __restrict__ stats1)
{
    const int tid = threadIdx.x;
    const int d = tid & 7;
    const size_t b = (size_t)blockIdx.x * 32 + (tid >> 3);

    float w0c[16][4], u0c[8][4], b0v[4];
    #pragma unroll
    for (int g = 0; g < 4; ++g) b0v[g] = b0[8*g + d];
    #pragma unroll
    for (int f = 0; f < 16; ++f)
        #pragma unroll
        for (int g = 0; g < 4; ++g) w0c[f][g] = W0[f*32 + 8*g + d];
    #pragma unroll
    for (int e = 0; e < 8; ++e)
        #pragma unroll
        for (int g = 0; g < 4; ++g) u0c[e][g] = U0[e*32 + 8*g + d];
    // pin all weights in VGPRs (~100 regs; fits the 256-reg budget at 2 waves/EU)
    #pragma unroll
    for (int f = 0; f < 16; ++f)
        #pragma unroll
        for (int g = 0; g < 4; ++g) KEEP(w0c[f][g]);
    #pragma unroll
    for (int e = 0; e < 8; ++e)
        #pragma unroll
        for (int g = 0; g < 4; ++g) KEEP(u0c[e][g]);
    #pragma unroll
    for (int g = 0; g < 4; ++g) KEEP(b0v[g]);

    const float4* __restrict__ xrow = reinterpret_cast<const float4*>(noise + b * 512);
    float h = 0.f, c = 0.f;
    // software-pipelined x: load t+1 while computing t
    float4 q0 = xrow[0], q1 = xrow[1], q2 = xrow[2], q3 = xrow[3];
    #pragma unroll 2
    for (int t = 0; t < 32; ++t){
        const float x[16] = {q0.x,q0.y,q0.z,q0.w, q1.x,q1.y,q1.z,q1.w,
                             q2.x,q2.y,q2.z,q2.w, q3.x,q3.y,q3.z,q3.w};
        const int tn = (t + 1) & 31;
        q0 = xrow[tn*4+0]; q1 = xrow[tn*4+1]; q2 = xrow[tn*4+2]; q3 = xrow[tn*4+3];
        float hall[8]; BC8_ALL(hall, h);
        float z[4] = {b0v[0], b0v[1], b0v[2], b0v[3]};
        #pragma unroll
        for (int f = 0; f < 16; ++f)
            #pragma unroll
            for (int g = 0; g < 4; ++g) z[g] = fmaf(x[f], w0c[f][g], z[g]);
        #pragma unroll
        for (int e = 0; e < 8; ++e)
            #pragma unroll
            for (int g = 0; g < 4; ++g) z[g] = fmaf(hall[e], u0c[e][g], z[g]);
        // gate order i,f,g,o -> z[0..3] for this unit
        c = sigm(z[1])*c + sigm(z[0])*tanh_fast(z[2]);
        h = sigm(z[3])*tanh_fast(c);
    }
    Hbuf[(size_t)blockIdx.x*256 + tid] = h;  // == b*8 + d, fully coalesced
    Cbuf[(size_t)blockIdx.x*256 + tid] = c;

    // BN1 stats: per-d sums of h, h^2, c, c^2
    float v0 = h, v1 = h*h, v2 = c, v3 = c*c;
    v0 += __shfl_down(v0,32); v0 += __shfl_down(v0,16); v0 += __shfl_down(v0,8);
    v1 += __shfl_down(v1,32); v1 += __shfl_down(v1,16); v1 += __shfl_down(v1,8);
    v2 += __shfl_down(v2,32); v2 += __shfl_down(v2,16); v2 += __shfl_down(v2,8);
    v3 += __shfl_down(v3,32); v3 += __shfl_down(v3,16); v3 += __shfl_down(v3,8);
    __shared__ float red[4][4][8];
    const int w = tid >> 6;
    if ((tid & 63) < 8){ red[0][w][d]=v0; red[1][w][d]=v1; red[2][w][d]=v2; red[3][w][d]=v3; }
    __syncthreads();
    if (tid < 32){
        const int s = tid >> 3, dd = tid & 7;
        float acc = red[s][0][dd] + red[s][1][dd] + red[s][2][dd] + red[s][3][dd];
        atomicAdd(stats1 + s*8 + dd, (double)acc);
    }
}

// ---------------- K2: BN1-apply + 14-step AR LSTM (relu), BN3 sums only -------
__global__ __launch_bounds__(256) void k2_ar(
    const float* __restrict__ Hbuf, const float* __restrict__ Cbuf,
    const double* __restrict__ stats1,
    const float* __restrict__ gamma_h, const float* __restrict__ beta_h,
    const float* __restrict__ gamma_c, const float* __restrict__ beta_c,
    const float* __restrict__ W1, const float* __restrict__ U1, const float* __restrict__ b1,
    double* __restrict__ stats3, int B)
{
    const int tid = threadIdx.x;
    const int d = tid & 7;
    const double invB = 1.0 / (double)B;
    const float meanH = (float)(stats1[d]      * invB);
    const float eH2   = (float)(stats1[8 + d]  * invB);
    const float meanC = (float)(stats1[16 + d] * invB);
    const float eC2   = (float)(stats1[24 + d] * invB);
    const float aH = gamma_h[d] * rsqrtf(eH2 - meanH*meanH + EPSV);
    const float aC = gamma_c[d] * rsqrtf(eC2 - meanC*meanC + EPSV);
    const float bH = beta_h[d] - meanH*aH;
    const float bC = beta_c[d] - meanC*aC;
    float h = fmaf(Hbuf[(size_t)blockIdx.x*256 + tid], aH, bH);
    float c = fmaf(Cbuf[(size_t)blockIdx.x*256 + tid], aC, bC);

    float wc[8][4], bcv[4];
    #pragma unroll
    for (int g = 0; g < 4; ++g) bcv[g] = b1[8*g + d];
    #pragma unroll
    for (int e = 0; e < 8; ++e)
        #pragma unroll
        for (int g = 0; g < 4; ++g) wc[e][g] = W1[e*32 + 8*g + d] + U1[e*32 + 8*g + d];

    float s1 = 0.f, s2 = 0.f;
    #pragma unroll
    for (int r = 0; r < 14; ++r){
        float hall[8]; BC8_ALL(hall, h);
        float z[4] = {bcv[0], bcv[1], bcv[2], bcv[3]};
        #pragma unroll
        for (int e = 0; e < 8; ++e)
            #pragma unroll
            for (int g = 0; g < 4; ++g) z[g] = fmaf(hall[e], wc[e][g], z[g]);
        c = sigm(z[1])*c + sigm(z[0])*fmaxf(z[2], 0.f);
        h = sigm(z[3])*fmaxf(c, 0.f);
        s1 += h; s2 = fmaf(h, h, s2);
    }
    s1 += __shfl_down(s1,32); s1 += __shfl_down(s1,16); s1 += __shfl_down(s1,8);
    s2 += __shfl_down(s2,32); s2 += __shfl_down(s2,16); s2 += __shfl_down(s2,8);
    __shared__ float red[2][4][8];
    const int w = tid >> 6;
    if ((tid & 63) < 8){ red[0][w][d] = s1; red[1][w][d] = s2; }
    __syncthreads();
    if (tid < 16){
        const int s = tid >> 3, dd = tid & 7;
        float acc = red[s][0][dd] + red[s][1][dd] + red[s][2][dd] + red[s][3][dd];
        atomicAdd(stats3 + s*8 + dd, (double)acc);
    }
}

// ---------------- K3: recompute AR LSTM, BN3-apply, output LSTM (8->4) --------
__global__ __launch_bounds__(256)
__attribute__((amdgpu_waves_per_eu(2, 2)))
void k3_out(
    const float* __restrict__ Hbuf, const float* __restrict__ Cbuf,
    const double* __restrict__ stats1, const double* __restrict__ stats3,
    const float* __restrict__ gamma_h, const float* __restrict__ beta_h,
    const float* __restrict__ gamma_c, const float* __restrict__ beta_c,
    const float* __restrict__ W1, const float* __restrict__ U1, const float* __restrict__ b1,
    const float* __restrict__ gamma3, const float* __restrict__ beta3,
    const float* __restrict__ W2, const float* __restrict__ U2, const float* __restrict__ b2,
    float* __restrict__ out, int B)
{
    const int tid = threadIdx.x;
    const int d = tid & 7;
    const double invB = 1.0 / (double)B;
    const float meanH = (float)(stats1[d]      * invB);
    const float eH2   = (float)(stats1[8 + d]  * invB);
    const float meanC = (float)(stats1[16 + d] * invB);
    const float eC2   = (float)(stats1[24 + d] * invB);
    const float aH = gamma_h[d] * rsqrtf(eH2 - meanH*meanH + EPSV);
    const float aC = gamma_c[d] * rsqrtf(eC2 - meanC*meanC + EPSV);
    const float bH = beta_h[d] - meanH*aH;
    const float bC = beta_c[d] - meanC*aC;
    float h = fmaf(Hbuf[(size_t)blockIdx.x*256 + tid], aH, bH);
    float c = fmaf(Cbuf[(size_t)blockIdx.x*256 + tid], aC, bC);

    float wc[8][4], bcv[4];
    #pragma unroll
    for (int g = 0; g < 4; ++g) bcv[g] = b1[8*g + d];
    #pragma unroll
    for (int e = 0; e < 8; ++e)
        #pragma unroll
        for (int g = 0; g < 4; ++g) wc[e][g] = W1[e*32 + 8*g + d] + U1[e*32 + 8*g + d];
    #pragma unroll
    for (int e = 0; e < 8; ++e)
        #pragma unroll
        for (int g = 0; g < 4; ++g) KEEP(wc[e][g]);

    float barh[14];
    #pragma unroll
    for (int r = 0; r < 14; ++r){
        float hall[8]; BC8_ALL(hall, h);
        float z[4] = {bcv[0], bcv[1], bcv[2], bcv[3]};
        #pragma unroll
        for (int e = 0; e < 8; ++e)
            #pragma unroll
            for (int g = 0; g < 4; ++g) z[g] = fmaf(hall[e], wc[e][g], z[g]);
        c = sigm(z[1])*c + sigm(z[0])*fmaxf(z[2], 0.f);
        h = sigm(z[3])*fmaxf(c, 0.f);
        barh[r] = h;
    }
    // BN3 over (B, ROWS)
    const double invN = 1.0 / ((double)B * 14.0);
    const float mean3 = (float)(stats3[d]     * invN);
    const float e32   = (float)(stats3[8 + d] * invN);
    const float a3 = gamma3[d] * rsqrtf(e32 - mean3*mean3 + EPSV);
    const float b3 = beta3[d] - mean3*a3;
    #pragma unroll
    for (int r = 0; r < 14; ++r) barh[r] = fmaf(barh[r], a3, b3);

    // output LSTM: Do=4; lanes 4-7 compute duplicates (q = d&3) so swizzles stay full-group
    const int q = d & 3;
    float w2c[8][4], u2c[4][4], b2v[4];
    #pragma unroll
    for (int g = 0; g < 4; ++g) b2v[g] = b2[4*g + q];
    #pragma unroll
    for (int e = 0; e < 8; ++e)
        #pragma unroll
        for (int g = 0; g < 4; ++g) w2c[e][g] = W2[e*16 + 4*g + q];
    #pragma unroll
    for (int e = 0; e < 4; ++e)
        #pragma unroll
        for (int g = 0; g < 4; ++g) u2c[e][g] = U2[e*16 + 4*g + q];
    #pragma unroll
    for (int e = 0; e < 8; ++e)
        #pragma unroll
        for (int g = 0; g < 4; ++g) KEEP(w2c[e][g]);
    #pragma unroll
    for (int e = 0; e < 4; ++e)
        #pragma unroll
        for (int g = 0; g < 4; ++g) KEEP(u2c[e][g]);

    float ho = 0.f, co = 0.f;
    const size_t obase = ((size_t)blockIdx.x*32 + (tid >> 3)) * 56;
    #pragma unroll
    for (int r = 0; r < 14; ++r){
        const float cur = barh[13 - r];            // bars = reversed hs
        float be[8]; BC8_ALL(be, cur);
        float h4[4];
        h4[0]=bc8<0>(ho); h4[1]=bc8<1>(ho); h4[2]=bc8<2>(ho); h4[3]=bc8<3>(ho);
        float z[4] = {b2v[0], b2v[1], b2v[2], b2v[3]};
        #pragma unroll
        for (int e = 0; e < 8; ++e)
            #pragma unroll
            for (int g = 0; g < 4; ++g) z[g] = fmaf(be[e], w2c[e][g], z[g]);
        #pragma unroll
        for (int e = 0; e < 4; ++e)
            #pragma unroll
            for (int g = 0; g < 4; ++g) z[g] = fmaf(h4[e], u2c[e][g], z[g]);
        co = sigm(z[1])*co + sigm(z[0])*fmaxf(z[2], 0.f);
        ho = sigm(z[3])*fmaxf(co, 0.f);
        if (d < 4) out[obase + r*4 + d] = ho;
    }
}

extern "C" void kernel_launch(void* const* d_in, const int* in_sizes, int n_in,
                              void* d_out, int out_size, void* d_ws, size_t ws_size,
                              hipStream_t stream)
{
    const float* noise   = (const float*)d_in[0];
    const float* W0      = (const float*)d_in[1];
    const float* U0      = (const float*)d_in[2];
    const float* b0      = (const float*)d_in[3];
    const float* gamma_h = (const float*)d_in[4];
    const float* beta_h  = (const float*)d_in[5];
    const float* gamma_c = (const float*)d_in[6];
    const float* beta_c  = (const float*)d_in[7];
    const float* W1      = (const float*)d_in[8];
    const float* U1      = (const float*)d_in[9];
    const float* b1      = (const float*)d_in[10];
    const float* gamma3  = (const float*)d_in[11];
    const float* beta3   = (const float*)d_in[12];
    const float* W2      = (const float*)d_in[13];
    const float* U2      = (const float*)d_in[14];
    const float* b2      = (const float*)d_in[15];

    const int B = in_sizes[0] / (32 * 16);   // 65536
    double* stats1 = (double*)d_ws;          // 32 doubles: Sh[8], Sh2[8], Sc[8], Sc2[8]
    double* stats3 = stats1 + 32;            // 16 doubles: Sb[8], Sb2[8]
    float* Hbuf = (float*)((char*)d_ws + 512);
    float* Cbuf = Hbuf + (size_t)B * 8;

    hipMemsetAsync(d_ws, 0, 48 * sizeof(double), stream);
    const int nb = B / 32;  // 2048 blocks x 256 threads, 8 lanes/sample
    k1_lstm0<<<nb, 256, 0, stream>>>(noise, W0, U0, b0, Hbuf, Cbuf, stats1);
    k2_ar<<<nb, 256, 0, stream>>>(Hbuf, Cbuf, stats1, gamma_h, beta_h, gamma_c, beta_c,
                                  W1, U1, b1, stats3, B);
    k3_out<<<nb, 256, 0, stream>>>(Hbuf, Cbuf, stats1, stats3, gamma_h, beta_h, gamma_c, beta_c,
                                   W1, U1, b1, gamma3, beta3, W2, U2, b2, (float*)d_out, B);
}